// Round 11
// baseline (711.382 us; speedup 1.0000x reference)
//
#include <hip/hip_runtime.h>
#include <stdint.h>
#include <math.h>

#define NEG 0.2f
#define TINYF 1.1754943508222875e-38f

typedef float f4 __attribute__((ext_vector_type(4)));
typedef float f2 __attribute__((ext_vector_type(2)));

// ---------------- Threefry-2x32-20 (matches JAX) ----------------
__host__ __device__ inline void threefry2x32(uint32_t k0, uint32_t k1,
                                             uint32_t x0, uint32_t x1,
                                             uint32_t* o0, uint32_t* o1) {
  uint32_t ks0 = k0, ks1 = k1, ks2 = k0 ^ k1 ^ 0x1BD11BDAu;
  x0 += ks0; x1 += ks1;
#define RR(r) { x0 += x1; x1 = (x1 << (r)) | (x1 >> (32 - (r))); x1 ^= x0; }
  RR(13) RR(15) RR(26) RR(6)
  x0 += ks1; x1 += ks2 + 1u;
  RR(17) RR(29) RR(16) RR(24)
  x0 += ks2; x1 += ks0 + 2u;
  RR(13) RR(15) RR(26) RR(6)
  x0 += ks0; x1 += ks1 + 3u;
  RR(17) RR(29) RR(16) RR(24)
  x0 += ks1; x1 += ks2 + 4u;
  RR(13) RR(15) RR(26) RR(6)
  x0 += ks2; x1 += ks0 + 5u;
#undef RR
  *o0 = x0; *o1 = x1;
}

// jax_threefry_partitionable=True random_bits, bit_width=32:
//   bits[i] = o0 ^ o1 of TF(key, (0, i))   [verified exact: R3-R10 pass]
__device__ inline float gumbel_part(uint32_t ka, uint32_t kb, uint32_t i) {
  uint32_t o0, o1;
  threefry2x32(ka, kb, 0u, i, &o0, &o1);
  uint32_t bits = o0 ^ o1;
  float f = __uint_as_float((bits >> 9) | 0x3f800000u) - 1.0f;
  float u = fmaxf(TINYF, f + TINYF);
  return -logf(-logf(u));
}

// ---------------- CSR build ----------------
__global__ void count_kernel(const int* __restrict__ ei, int E, int* __restrict__ counts) {
  int e = blockIdx.x * blockDim.x + threadIdx.x;
  if (e < E) atomicAdd(&counts[ei[E + e]], 1);
}

// parallel scan, 3 phases
#define SCB 256
__global__ __launch_bounds__(256) void scan_partial_kernel(const int* __restrict__ counts,
    int N, int chunk, int* __restrict__ bsum) {
  int b = blockIdx.x;
  int s0 = b * chunk, s1 = s0 + chunk; if (s1 > N) s1 = N;
  int tid = threadIdx.x;
  int v = 0;
  for (int i = s0 + tid; i < s1; i += 256) v += counts[i];
  __shared__ int red[256];
  red[tid] = v; __syncthreads();
  for (int s = 128; s; s >>= 1) { if (tid < s) red[tid] += red[tid + s]; __syncthreads(); }
  if (tid == 0) bsum[b] = red[0];
}

__global__ __launch_bounds__(256) void scan_offsets_kernel(const int* __restrict__ bsum,
    int* __restrict__ boff, int* __restrict__ row_start, int N) {
  int tid = threadIdx.x; int lane = tid & 63; int wv = tid >> 6;
  __shared__ int wsum[4];
  int v = bsum[tid];
  int incl = v;
#pragma unroll
  for (int off = 1; off < 64; off <<= 1) {
    int t = __shfl_up(incl, off);
    if (lane >= off) incl += t;
  }
  if (lane == 63) wsum[wv] = incl;
  __syncthreads();
  if (tid == 0) {
    int s = 0;
    for (int k = 0; k < 4; k++) { int t = wsum[k]; wsum[k] = s; s += t; }
    row_start[N] = s;
  }
  __syncthreads();
  boff[tid] = wsum[wv] + incl - v;
}

__global__ __launch_bounds__(256) void scan_apply_kernel(const int* __restrict__ counts,
    const int* __restrict__ boff, int N, int chunk,
    int* __restrict__ row_start, int* __restrict__ cursor) {
  int b = blockIdx.x;
  int s0 = b * chunk, s1 = s0 + chunk; if (s1 > N) s1 = N;
  int tid = threadIdx.x; int lane = tid & 63; int wv = tid >> 6;
  __shared__ int wsum[4];
  __shared__ int tot_s;
  __shared__ int base_s;
  if (tid == 0) base_s = boff[b];
  __syncthreads();
  for (int c0 = s0; c0 < s1; c0 += 256) {
    int i = c0 + tid;
    int v = (i < s1) ? counts[i] : 0;
    int incl = v;
#pragma unroll
    for (int off = 1; off < 64; off <<= 1) {
      int t = __shfl_up(incl, off);
      if (lane >= off) incl += t;
    }
    if (lane == 63) wsum[wv] = incl;
    __syncthreads();
    if (tid == 0) {
      int s = 0;
      for (int k = 0; k < 4; k++) { int t = wsum[k]; wsum[k] = s; s += t; }
      tot_s = s;
    }
    __syncthreads();
    int base = base_s;
    int excl = base + wsum[wv] + incl - v;
    if (i < s1) { row_start[i] = excl; cursor[i] = excl; }
    __syncthreads();
    if (tid == 0) base_s = base + tot_s;
    __syncthreads();
  }
}

// scatter: src_csr + ea permuted into CSR order (streamed reads downstream)
__global__ void scatter_kernel(const int* __restrict__ ei, const float* __restrict__ ea,
                               int E, int* __restrict__ cursor,
                               int* __restrict__ src_csr, float* __restrict__ ea_csr) {
  int e = blockIdx.x * blockDim.x + threadIdx.x;
  if (e < E) {
    int d = ei[E + e];
    int p = atomicAdd(&cursor[d], 1);
    src_csr[p] = ei[e];
    const float4* s4 = (const float4*)&ea[(size_t)e * 16];
    float4* d4 = (float4*)&ea_csr[(size_t)p * 16];
    float4 t0 = s4[0], t1 = s4[1], t2 = s4[2], t3 = s4[3];
    d4[0] = t0; d4[1] = t1; d4[2] = t2; d4[3] = t3;
  }
}

// ---------------- h = X @ W (128x128) + b ----------------
__global__ __launch_bounds__(256) void gemm128_kernel(const float* __restrict__ X,
    const float* __restrict__ W, const float* __restrict__ bias,
    float* __restrict__ out, int M) {
  __shared__ float xs[128][33];
  int row0 = blockIdx.x * 32;
  int tid = threadIdx.x;
  for (int idx = tid; idx < 32 * 128; idx += 256) {
    int r = idx >> 7;
    int k = idx & 127;
    int row = row0 + r;
    xs[k][r] = (row < M) ? X[(size_t)row * 128 + k] : 0.0f;
  }
  __syncthreads();
  int tc = tid & 31, tr = tid >> 5;
  int c0 = tc * 4, r0 = tr * 4;
  float acc[4][4] = {};
#pragma unroll 4
  for (int k = 0; k < 128; k++) {
    float4 w = *(const float4*)&W[k * 128 + c0];
    float x0 = xs[k][r0], x1 = xs[k][r0 + 1], x2 = xs[k][r0 + 2], x3 = xs[k][r0 + 3];
    acc[0][0] += x0 * w.x; acc[0][1] += x0 * w.y; acc[0][2] += x0 * w.z; acc[0][3] += x0 * w.w;
    acc[1][0] += x1 * w.x; acc[1][1] += x1 * w.y; acc[1][2] += x1 * w.z; acc[1][3] += x1 * w.w;
    acc[2][0] += x2 * w.x; acc[2][1] += x2 * w.y; acc[2][2] += x2 * w.z; acc[2][3] += x2 * w.w;
    acc[3][0] += x3 * w.x; acc[3][1] += x3 * w.y; acc[3][2] += x3 * w.z; acc[3][3] += x3 * w.w;
  }
  float4 b4 = *(const float4*)&bias[c0];
  for (int r = 0; r < 4; r++) {
    int row = row0 + r0 + r;
    if (row < M) {
      float4 o;
      o.x = acc[r][0] + b4.x; o.y = acc[r][1] + b4.y;
      o.z = acc[r][2] + b4.z; o.w = acc[r][3] + b4.w;
      *(float4*)&out[(size_t)row * 128 + c0] = o;
    }
  }
}

// ---------------- ch[node*40 + {0..31}] = latent @ Wl3 + b ----------------
__global__ __launch_bounds__(256) void gemm32_kernel(const float* __restrict__ X,
    const float* __restrict__ W, const float* __restrict__ bias,
    float* __restrict__ ch, int M) {
  int t = blockIdx.x * 256 + threadIdx.x;
  int node = t >> 5, c = t & 31;
  if (node >= M) return;
  const float4* xp = (const float4*)&X[(size_t)node * 128];
  float acc = 0.f;
#pragma unroll
  for (int q = 0; q < 32; q++) {
    float4 x4 = xp[q];
    acc += x4.x * W[(q * 4 + 0) * 32 + c] + x4.y * W[(q * 4 + 1) * 32 + c]
         + x4.z * W[(q * 4 + 2) * 32 + c] + x4.w * W[(q * 4 + 3) * 32 + c];
  }
  ch[(size_t)node * 40 + c] = acc + bias[c];
}

// ---------------- ch[node*40 + 32] = latent @ Wl2 + b ----------------
__global__ __launch_bounds__(256) void gemv_kernel(const float* __restrict__ X,
    const float* __restrict__ w, const float* __restrict__ b0,
    float* __restrict__ ch, int M) {
  int wv = (blockIdx.x * 256 + threadIdx.x) >> 6;
  int lane = threadIdx.x & 63;
  if (wv >= M) return;
  float2 xv = *(const float2*)&X[(size_t)wv * 128 + lane * 2];
  float2 wvv = *(const float2*)&w[lane * 2];
  float v = xv.x * wvv.x + xv.y * wvv.y;
#pragma unroll
  for (int off = 32; off; off >>= 1) v += __shfl_xor(v, off);
  if (lane == 0) ch[(size_t)wv * 40 + 32] = v + b0[0];
}

// ---------------- layer-1 fused: half-wave/node, k-chunked 4-edge-batch MAC ----------------
// LDS We rows loaded once per 4 edges (not per edge): LDS traffic/edge 256->64 B/lane.
__global__ __launch_bounds__(256) void fused1_kernel(const float* __restrict__ h,
    const int* __restrict__ src_csr, const int* __restrict__ row_start,
    const float* __restrict__ ea_csr,
    const float* __restrict__ We, const float* __restrict__ att,
    const float* __restrict__ bias, float* __restrict__ out, int N) {
  __shared__ float WeS[2048];
  int tid = threadIdx.x;
  for (int i = tid; i < 2048; i += 256) WeS[i] = We[i];
  __syncthreads();
  int hw = (blockIdx.x * 256 + tid) >> 5;   // half-wave = one node
  int lane = tid & 31;
  if (hw >= N) return;
  int c4 = lane * 4;
  const f4* W4 = (const f4*)WeS;            // row k at W4[k*32 + lane]
  f4 attv = *(const f4*)&att[c4];
  f4 bb = *(const f4*)&bias[c4];
  int start = row_start[hw];
  int deg = row_start[hw + 1] - start;
  if (deg == 0) {
    *(f4*)&out[(size_t)hw * 128 + c4] = bb;
    return;
  }
  f4 hi = *(const f4*)&h[(size_t)hw * 128 + c4];
  int s_l = (lane < deg) ? src_csr[start + lane] : 0;
  int dcap = deg < 32 ? deg : 32;
  const f4* eap = (const f4*)&ea_csr[(size_t)start * 16];
  float m = -INFINITY, l = 0.f;
  f4 acc = (f4)0.f;
  for (int j0 = 0; j0 < deg; j0 += 4) {
    // gather batch hj up-front (latency covered by the MAC block below)
    f4 hj[4];
    int jc[4];
#pragma unroll
    for (int t = 0; t < 4; t++) {
      int j = j0 + t;
      jc[t] = (j < deg) ? j : j0;
      int s = (jc[t] < dcap) ? __shfl(s_l, jc[t], 32) : src_csr[start + jc[t]];
      hj[t] = *(const f4*)&h[(size_t)s * 128 + c4];
    }
    // k-chunked MAC: 4 We rows reused across the 4-edge batch
    f4 vb0 = (f4)0.f, vb1 = (f4)0.f, vb2 = (f4)0.f, vb3 = (f4)0.f;
#pragma unroll
    for (int kc = 0; kc < 4; kc++) {
      f4 w0 = W4[(4 * kc + 0) * 32 + lane];
      f4 w1 = W4[(4 * kc + 1) * 32 + lane];
      f4 w2 = W4[(4 * kc + 2) * 32 + lane];
      f4 w3 = W4[(4 * kc + 3) * 32 + lane];
      {
        f4 aq = eap[(size_t)jc[0] * 4 + kc];
        vb0 += aq.x * w0 + aq.y * w1 + aq.z * w2 + aq.w * w3;
      }
      {
        f4 aq = eap[(size_t)jc[1] * 4 + kc];
        vb1 += aq.x * w0 + aq.y * w1 + aq.z * w2 + aq.w * w3;
      }
      {
        f4 aq = eap[(size_t)jc[2] * 4 + kc];
        vb2 += aq.x * w0 + aq.y * w1 + aq.z * w2 + aq.w * w3;
      }
      {
        f4 aq = eap[(size_t)jc[3] * 4 + kc];
        vb3 += aq.x * w0 + aq.y * w1 + aq.z * w2 + aq.w * w3;
      }
    }
    // scores
    float sc[4];
#pragma unroll
    for (int t = 0; t < 4; t++) {
      f4 v = (t == 0 ? vb0 : t == 1 ? vb1 : t == 2 ? vb2 : vb3) + hi + hj[t];
      v.x = v.x >= 0.f ? v.x : NEG * v.x;
      v.y = v.y >= 0.f ? v.y : NEG * v.y;
      v.z = v.z >= 0.f ? v.z : NEG * v.z;
      v.w = v.w >= 0.f ? v.w : NEG * v.w;
      f4 pv = v * attv;
      sc[t] = (pv.x + pv.y) + (pv.z + pv.w);
    }
#pragma unroll
    for (int off = 16; off; off >>= 1) {
      sc[0] += __shfl_xor(sc[0], off);
      sc[1] += __shfl_xor(sc[1], off);
      sc[2] += __shfl_xor(sc[2], off);
      sc[3] += __shfl_xor(sc[3], off);
    }
    if (j0 + 1 >= deg) sc[1] = -INFINITY;
    if (j0 + 2 >= deg) sc[2] = -INFINITY;
    if (j0 + 3 >= deg) sc[3] = -INFINITY;
    float mb = fmaxf(fmaxf(sc[0], sc[1]), fmaxf(sc[2], sc[3]));
    float mn = fmaxf(m, mb);
    float scale = __expf(m - mn);   // first batch: exp(-inf)=0
    float w0 = __expf(sc[0] - mn);
    float w1 = __expf(sc[1] - mn);
    float w2 = __expf(sc[2] - mn);
    float w3 = __expf(sc[3] - mn);
    l = l * scale + ((w0 + w1) + (w2 + w3));
    acc = acc * scale + w0 * hj[0] + w1 * hj[1] + w2 * hj[2] + w3 * hj[3];
    m = mn;
  }
  float inv = 1.0f / (l + 1e-16f);
  f4 o = acc * inv + bb;
  *(f4*)&out[(size_t)hw * 128 + c4] = o;
}

// ---------------- layers 2+3 fused (wave/node, quarter-wave/edge, LDS weights,
//                  single combined ch gather stream) ----------------
__global__ __launch_bounds__(256) void fused23_kernel(
    const float* __restrict__ ch,
    const int* __restrict__ src_csr, const int* __restrict__ row_start,
    const float* __restrict__ ea_csr,
    const float* __restrict__ We3, const float* __restrict__ att3,
    const float* __restrict__ bias3, const float* __restrict__ We2,
    const float* __restrict__ att2, const float* __restrict__ bias2,
    float* __restrict__ out3, float* __restrict__ logits, int N) {
  __shared__ float We3S[512];
  __shared__ float att3S[32];
  __shared__ float We2S[16];
  int tid = threadIdx.x;
  for (int i = tid; i < 512; i += 256) We3S[i] = We3[i];
  if (tid < 32) att3S[tid] = att3[tid];
  if (tid < 16) We2S[tid] = We2[tid];
  __syncthreads();
  int wv = (blockIdx.x * 256 + tid) >> 6;
  int lane = tid & 63;
  if (wv >= N) return;
  int q4 = lane >> 4;        // quarter index 0..3
  int l16 = lane & 15;
  int c2 = l16 * 2;          // 2 dims per lane
  const f2* W3 = (const f2*)We3S;   // row k at W3[k*16 + l16]
  f2 at3 = *(const f2*)&att3S[c2];
  float a2s = att2[0];
  f2 bi3 = *(const f2*)&bias3[c2];
  int start = row_start[wv];
  int deg = row_start[wv + 1] - start;
  if (deg == 0) {
    if (lane < 16) *(f2*)&out3[(size_t)wv * 32 + c2] = bi3;
    if (lane == 0) logits[wv] = bias2[0];
    return;
  }
  f2 hi3 = *(const f2*)&ch[(size_t)wv * 40 + c2];
  float hi2 = ch[(size_t)wv * 40 + 32];
  int s_l = (lane < deg) ? src_csr[start + lane] : 0;
  int dcap = deg < 64 ? deg : 64;
  const float4* eap = (const float4*)&ea_csr[(size_t)start * 16];
  float m3 = -INFINITY, l3 = 0.f; f2 a3 = (f2)0.f;
  float m2 = -INFINITY, l2 = 0.f; float a2 = 0.f;
  for (int j = q4; j < deg; j += 4) {
    int s = (j < dcap) ? __shfl(s_l, j) : src_csr[start + j];
    f2 hj3 = *(const f2*)&ch[(size_t)s * 40 + c2];
    float h2s = ch[(size_t)s * 40 + 32];
    float4 c0 = eap[(size_t)j * 4 + 0];
    float4 c1 = eap[(size_t)j * 4 + 1];
    float4 cc2 = eap[(size_t)j * 4 + 2];
    float4 c3 = eap[(size_t)j * 4 + 3];
    f2 v = hi3 + hj3;
    v += c0.x * W3[0 * 16 + l16];  v += c0.y * W3[1 * 16 + l16];
    v += c0.z * W3[2 * 16 + l16];  v += c0.w * W3[3 * 16 + l16];
    v += c1.x * W3[4 * 16 + l16];  v += c1.y * W3[5 * 16 + l16];
    v += c1.z * W3[6 * 16 + l16];  v += c1.w * W3[7 * 16 + l16];
    v += cc2.x * W3[8 * 16 + l16]; v += cc2.y * W3[9 * 16 + l16];
    v += cc2.z * W3[10 * 16 + l16]; v += cc2.w * W3[11 * 16 + l16];
    v += c3.x * W3[12 * 16 + l16]; v += c3.y * W3[13 * 16 + l16];
    v += c3.z * W3[14 * 16 + l16]; v += c3.w * W3[15 * 16 + l16];
    v.x = v.x >= 0.f ? v.x : NEG * v.x;
    v.y = v.y >= 0.f ? v.y : NEG * v.y;
    float t3 = v.x * at3.x + v.y * at3.y;
#pragma unroll
    for (int off = 8; off; off >>= 1) t3 += __shfl_xor(t3, off);
    float v2 = hi2 + h2s;
    v2 += c0.x * We2S[0]  + c0.y * We2S[1]  + c0.z * We2S[2]  + c0.w * We2S[3];
    v2 += c1.x * We2S[4]  + c1.y * We2S[5]  + c1.z * We2S[6]  + c1.w * We2S[7];
    v2 += cc2.x * We2S[8] + cc2.y * We2S[9] + cc2.z * We2S[10] + cc2.w * We2S[11];
    v2 += c3.x * We2S[12] + c3.y * We2S[13] + c3.z * We2S[14] + c3.w * We2S[15];
    v2 = v2 >= 0.f ? v2 : NEG * v2;
    float t2 = v2 * a2s;
    float mn3 = fmaxf(m3, t3);
    float sc3 = __expf(m3 - mn3);
    float w3 = __expf(t3 - mn3);
    l3 = l3 * sc3 + w3;
    a3 = a3 * sc3 + w3 * hj3;
    m3 = mn3;
    float mn2 = fmaxf(m2, t2);
    float sc2 = __expf(m2 - mn2);
    float w2 = __expf(t2 - mn2);
    l2 = l2 * sc2 + w2;
    a2 = a2 * sc2 + w2 * h2s;
    m2 = mn2;
  }
  // merge 4 quarter states (xor 16 then 32); quarter 0 has >=1 edge
#pragma unroll
  for (int off = 16; off <= 32; off <<= 1) {
    float m3o = __shfl_xor(m3, off), l3o = __shfl_xor(l3, off);
    float ax = __shfl_xor(a3.x, off), ay = __shfl_xor(a3.y, off);
    float M3 = fmaxf(m3, m3o);
    float sA = (m3 == -INFINITY) ? 0.f : __expf(m3 - M3);
    float sB = (m3o == -INFINITY) ? 0.f : __expf(m3o - M3);
    l3 = l3 * sA + l3o * sB;
    a3.x = a3.x * sA + ax * sB;
    a3.y = a3.y * sA + ay * sB;
    m3 = M3;
    float m2o = __shfl_xor(m2, off), l2o = __shfl_xor(l2, off);
    float az = __shfl_xor(a2, off);
    float M2 = fmaxf(m2, m2o);
    float tA = (m2 == -INFINITY) ? 0.f : __expf(m2 - M2);
    float tB = (m2o == -INFINITY) ? 0.f : __expf(m2o - M2);
    l2 = l2 * tA + l2o * tB;
    a2 = a2 * tA + az * tB;
    m2 = M2;
  }
  if (lane < 16) {
    f2 o;
    o.x = a3.x / (l3 + 1e-16f) + bi3.x;
    o.y = a3.y / (l3 + 1e-16f) + bi3.y;
    *(f2*)&out3[(size_t)wv * 32 + c2] = o;
  }
  if (lane == 0) logits[wv] = a2 / (l2 + 1e-16f) + bias2[0];
}

// ---------------- node categorical: 64-block partial + 1-wave final ----------------
#define NSB 64
__global__ __launch_bounds__(256) void node_partial_kernel(const float* __restrict__ logits,
    int N, uint32_t ka, uint32_t kb,
    float* __restrict__ pB, int* __restrict__ pI,
    float* __restrict__ pM, float* __restrict__ pL) {
  int chunk = (N + NSB - 1) / NSB;
  int s0 = blockIdx.x * chunk;
  int s1 = s0 + chunk; if (s1 > N) s1 = N;
  int tid = threadIdx.x;
  float best = -INFINITY; int bi = 0x7fffffff;
  float m = -INFINITY, l = 0.f;
  for (int i = s0 + tid; i < s1; i += 256) {
    float lg = logits[i];
    float mn = fmaxf(m, lg);
    l = l * __expf(m - mn) + __expf(lg - mn);
    m = mn;
    float v = lg + gumbel_part(ka, kb, (uint32_t)i);
    if (v > best) { best = v; bi = i; }
  }
  __shared__ float sb[256], sm[256], sl[256];
  __shared__ int si[256];
  sb[tid] = best; si[tid] = bi; sm[tid] = m; sl[tid] = l;
  __syncthreads();
  for (int s = 128; s; s >>= 1) {
    if (tid < s) {
      if (sb[tid + s] > sb[tid] || (sb[tid + s] == sb[tid] && si[tid + s] < si[tid])) {
        sb[tid] = sb[tid + s]; si[tid] = si[tid + s];
      }
      float M = fmaxf(sm[tid], sm[tid + s]);
      float t0 = (sm[tid] == -INFINITY) ? 0.f : sl[tid] * __expf(sm[tid] - M);
      float t1 = (sm[tid + s] == -INFINITY) ? 0.f : sl[tid + s] * __expf(sm[tid + s] - M);
      sm[tid] = M; sl[tid] = t0 + t1;
    }
    __syncthreads();
  }
  if (tid == 0) { pB[blockIdx.x] = sb[0]; pI[blockIdx.x] = si[0]; pM[blockIdx.x] = sm[0]; pL[blockIdx.x] = sl[0]; }
}

__global__ __launch_bounds__(64) void node_final_kernel(const float* __restrict__ logits,
    const float* __restrict__ pB, const int* __restrict__ pI,
    const float* __restrict__ pM, const float* __restrict__ pL,
    float* __restrict__ scal) {
  int lane = threadIdx.x;
  float best = pB[lane]; int bi = pI[lane];
  float m = pM[lane]; float l = pL[lane];
#pragma unroll
  for (int off = 32; off; off >>= 1) {
    float ob = __shfl_xor(best, off); int oi = __shfl_xor(bi, off);
    if (ob > best || (ob == best && oi < bi)) { best = ob; bi = oi; }
    float om = __shfl_xor(m, off); float ol = __shfl_xor(l, off);
    float M = fmaxf(m, om);
    float t0 = (m == -INFINITY) ? 0.f : l * __expf(m - M);
    float t1 = (om == -INFINITY) ? 0.f : ol * __expf(om - M);
    m = M; l = t0 + t1;
  }
  if (lane == 0) {
    ((int*)scal)[0] = bi;
    scal[3] = logits[bi] - (m + logf(l));
  }
}

// ---------------- action categorical + output ----------------
__global__ __launch_bounds__(64) void action_kernel(const float* __restrict__ out3,
    const float* __restrict__ scal, uint32_t ka, uint32_t kb,
    float* __restrict__ dout, int out_size) {
  int lane = threadIdx.x;
  int sel = ((const int*)scal)[0];
  float v = -INFINITY, noisy = -INFINITY;
  if (lane < 32) {
    v = out3[(size_t)sel * 32 + lane];
    noisy = v + gumbel_part(ka, kb, (uint32_t)lane);
  }
  int idx = lane;
  float nv = noisy;
#pragma unroll
  for (int off = 32; off; off >>= 1) {
    float ov = __shfl_xor(nv, off);
    int oi = __shfl_xor(idx, off);
    if (ov > nv || (ov == nv && oi < idx)) { nv = ov; idx = oi; }
  }
  float vm = v;
#pragma unroll
  for (int off = 32; off; off >>= 1) vm = fmaxf(vm, __shfl_xor(vm, off));
  float ex = (lane < 32) ? expf(v - vm) : 0.f;
#pragma unroll
  for (int off = 32; off; off >>= 1) ex += __shfl_xor(ex, off);
  float vsel = __shfl(v, idx);
  if (lane == 0) {
    float action_lp = vsel - vm - logf(ex);
    dout[0] = (float)sel;
    dout[1] = (float)idx;
    dout[2] = scal[3] + action_lp;
  }
  for (int i = 3 + lane; i < out_size; i += 64) dout[i] = 0.f;
}

extern "C" void kernel_launch(void* const* d_in, const int* in_sizes, int n_in,
                              void* d_out, int out_size, void* d_ws, size_t ws_size,
                              hipStream_t stream) {
  const float* x     = (const float*)d_in[0];
  const int*   ei    = (const int*)d_in[1];
  const float* ea    = (const float*)d_in[2];
  const float* Wl1   = (const float*)d_in[3];
  const float* bl1   = (const float*)d_in[4];
  const float* We1   = (const float*)d_in[5];
  const float* att1  = (const float*)d_in[6];
  const float* bias1 = (const float*)d_in[7];
  const float* Wl2   = (const float*)d_in[8];
  const float* bl2   = (const float*)d_in[9];
  const float* We2   = (const float*)d_in[10];
  const float* att2  = (const float*)d_in[11];
  const float* bias2 = (const float*)d_in[12];
  const float* Wl3   = (const float*)d_in[13];
  const float* bl3   = (const float*)d_in[14];
  const float* We3   = (const float*)d_in[15];
  const float* att3  = (const float*)d_in[16];
  const float* bias3 = (const float*)d_in[17];
  int N = in_sizes[0] / 128;
  int E = in_sizes[1] / 2;
  float* out = (float*)d_out;

  char* p = (char*)d_ws;
  auto alloc = [&](size_t bytes) -> char* {
    char* r = p; p += (bytes + 255) & ~(size_t)255; return r;
  };
  float* h1      = (float*)alloc((size_t)N * 128 * 4);
  float* latent  = (float*)alloc((size_t)N * 128 * 4);
  float* ch      = (float*)alloc((size_t)N * 40 * 4);   // h3 dims 0-31, h2 at 32
  float* logits  = (float*)alloc((size_t)N * 4);
  float* out3    = (float*)alloc((size_t)N * 32 * 4);
  int* counts    = (int*)alloc((size_t)N * 4);
  int* row_start = (int*)alloc((size_t)(N + 1) * 4);
  int* cursor    = (int*)alloc((size_t)N * 4);
  int* src_csr   = (int*)alloc((size_t)E * 4);
  float* ea_csr  = (float*)alloc((size_t)E * 16 * 4);
  int* bsum      = (int*)alloc(SCB * 4);
  int* boff      = (int*)alloc(SCB * 4);
  float* pB      = (float*)alloc(NSB * 4);
  int*   pI      = (int*)alloc(NSB * 4);
  float* pM      = (float*)alloc(NSB * 4);
  float* pL      = (float*)alloc(NSB * 4);
  float* scal    = (float*)alloc(64);
  (void)ws_size; (void)n_in;

  // JAX PRNG (partitionable): key(42)=(0,42); subkey_i = TF(key,(0,i))
  uint32_t k1a, k1b, k2a, k2b;
  threefry2x32(0u, 42u, 0u, 0u, &k1a, &k1b);
  threefry2x32(0u, 42u, 0u, 1u, &k2a, &k2b);

  int chunk = (N + SCB - 1) / SCB;

  hipMemsetAsync(counts, 0, (size_t)N * 4, stream);
  count_kernel<<<(E + 255) / 256, 256, 0, stream>>>(ei, E, counts);
  scan_partial_kernel<<<SCB, 256, 0, stream>>>(counts, N, chunk, bsum);
  scan_offsets_kernel<<<1, 256, 0, stream>>>(bsum, boff, row_start, N);
  scan_apply_kernel<<<SCB, 256, 0, stream>>>(counts, boff, N, chunk, row_start, cursor);
  scatter_kernel<<<(E + 255) / 256, 256, 0, stream>>>(ei, ea, E, cursor, src_csr, ea_csr);

  gemm128_kernel<<<(N + 31) / 32, 256, 0, stream>>>(x, Wl1, bl1, h1, N);
  fused1_kernel<<<(N + 7) / 8, 256, 0, stream>>>(h1, src_csr, row_start,
                                                 ea_csr, We1, att1, bias1, latent, N);

  gemm32_kernel<<<((size_t)N * 32 + 255) / 256, 256, 0, stream>>>(latent, Wl3, bl3, ch, N);
  gemv_kernel<<<(N + 3) / 4, 256, 0, stream>>>(latent, Wl2, bl2, ch, N);

  fused23_kernel<<<(N + 3) / 4, 256, 0, stream>>>(ch, src_csr, row_start, ea_csr,
                                                  We3, att3, bias3, We2, att2, bias2,
                                                  out3, logits, N);

  node_partial_kernel<<<NSB, 256, 0, stream>>>(logits, N, k1a, k1b, pB, pI, pM, pL);
  node_final_kernel<<<1, 64, 0, stream>>>(logits, pB, pI, pM, pL, scal);
  action_kernel<<<1, 64, 0, stream>>>(out3, scal, k2a, k2b, out, out_size);
}

// Round 12
// 681.759 us; speedup vs baseline: 1.0435x; 1.0435x over previous
//
#include <hip/hip_runtime.h>
#include <stdint.h>
#include <math.h>

#define NEG 0.2f
#define TINYF 1.1754943508222875e-38f

typedef float f4 __attribute__((ext_vector_type(4)));
typedef float f2 __attribute__((ext_vector_type(2)));

// ---------------- Threefry-2x32-20 (matches JAX) ----------------
__host__ __device__ inline void threefry2x32(uint32_t k0, uint32_t k1,
                                             uint32_t x0, uint32_t x1,
                                             uint32_t* o0, uint32_t* o1) {
  uint32_t ks0 = k0, ks1 = k1, ks2 = k0 ^ k1 ^ 0x1BD11BDAu;
  x0 += ks0; x1 += ks1;
#define RR(r) { x0 += x1; x1 = (x1 << (r)) | (x1 >> (32 - (r))); x1 ^= x0; }
  RR(13) RR(15) RR(26) RR(6)
  x0 += ks1; x1 += ks2 + 1u;
  RR(17) RR(29) RR(16) RR(24)
  x0 += ks2; x1 += ks0 + 2u;
  RR(13) RR(15) RR(26) RR(6)
  x0 += ks0; x1 += ks1 + 3u;
  RR(17) RR(29) RR(16) RR(24)
  x0 += ks1; x1 += ks2 + 4u;
  RR(13) RR(15) RR(26) RR(6)
  x0 += ks2; x1 += ks0 + 5u;
#undef RR
  *o0 = x0; *o1 = x1;
}

// jax_threefry_partitionable=True random_bits, bit_width=32:
//   bits[i] = o0 ^ o1 of TF(key, (0, i))   [verified exact: R3-R11 pass]
__device__ inline float gumbel_part(uint32_t ka, uint32_t kb, uint32_t i) {
  uint32_t o0, o1;
  threefry2x32(ka, kb, 0u, i, &o0, &o1);
  uint32_t bits = o0 ^ o1;
  float f = __uint_as_float((bits >> 9) | 0x3f800000u) - 1.0f;
  float u = fmaxf(TINYF, f + TINYF);
  return -logf(-logf(u));
}

// ---------------- CSR build ----------------
__global__ void count_kernel(const int* __restrict__ ei, int E, int* __restrict__ counts) {
  int e = blockIdx.x * blockDim.x + threadIdx.x;
  if (e < E) atomicAdd(&counts[ei[E + e]], 1);
}

// parallel scan, 3 phases
#define SCB 256
__global__ __launch_bounds__(256) void scan_partial_kernel(const int* __restrict__ counts,
    int N, int chunk, int* __restrict__ bsum) {
  int b = blockIdx.x;
  int s0 = b * chunk, s1 = s0 + chunk; if (s1 > N) s1 = N;
  int tid = threadIdx.x;
  int v = 0;
  for (int i = s0 + tid; i < s1; i += 256) v += counts[i];
  __shared__ int red[256];
  red[tid] = v; __syncthreads();
  for (int s = 128; s; s >>= 1) { if (tid < s) red[tid] += red[tid + s]; __syncthreads(); }
  if (tid == 0) bsum[b] = red[0];
}

__global__ __launch_bounds__(256) void scan_offsets_kernel(const int* __restrict__ bsum,
    int* __restrict__ boff, int* __restrict__ row_start, int N) {
  int tid = threadIdx.x; int lane = tid & 63; int wv = tid >> 6;
  __shared__ int wsum[4];
  int v = bsum[tid];
  int incl = v;
#pragma unroll
  for (int off = 1; off < 64; off <<= 1) {
    int t = __shfl_up(incl, off);
    if (lane >= off) incl += t;
  }
  if (lane == 63) wsum[wv] = incl;
  __syncthreads();
  if (tid == 0) {
    int s = 0;
    for (int k = 0; k < 4; k++) { int t = wsum[k]; wsum[k] = s; s += t; }
    row_start[N] = s;
  }
  __syncthreads();
  boff[tid] = wsum[wv] + incl - v;
}

__global__ __launch_bounds__(256) void scan_apply_kernel(const int* __restrict__ counts,
    const int* __restrict__ boff, int N, int chunk,
    int* __restrict__ row_start, int* __restrict__ cursor) {
  int b = blockIdx.x;
  int s0 = b * chunk, s1 = s0 + chunk; if (s1 > N) s1 = N;
  int tid = threadIdx.x; int lane = tid & 63; int wv = tid >> 6;
  __shared__ int wsum[4];
  __shared__ int tot_s;
  __shared__ int base_s;
  if (tid == 0) base_s = boff[b];
  __syncthreads();
  for (int c0 = s0; c0 < s1; c0 += 256) {
    int i = c0 + tid;
    int v = (i < s1) ? counts[i] : 0;
    int incl = v;
#pragma unroll
    for (int off = 1; off < 64; off <<= 1) {
      int t = __shfl_up(incl, off);
      if (lane >= off) incl += t;
    }
    if (lane == 63) wsum[wv] = incl;
    __syncthreads();
    if (tid == 0) {
      int s = 0;
      for (int k = 0; k < 4; k++) { int t = wsum[k]; wsum[k] = s; s += t; }
      tot_s = s;
    }
    __syncthreads();
    int base = base_s;
    int excl = base + wsum[wv] + incl - v;
    if (i < s1) { row_start[i] = excl; cursor[i] = excl; }
    __syncthreads();
    if (tid == 0) base_s = base + tot_s;
    __syncthreads();
  }
}

// scatter: src_csr, dst_csr + ea permuted into CSR order
__global__ void scatter_kernel(const int* __restrict__ ei, const float* __restrict__ ea,
                               int E, int* __restrict__ cursor,
                               int* __restrict__ src_csr, int* __restrict__ dst_csr,
                               float* __restrict__ ea_csr) {
  int e = blockIdx.x * blockDim.x + threadIdx.x;
  if (e < E) {
    int d = ei[E + e];
    int p = atomicAdd(&cursor[d], 1);
    src_csr[p] = ei[e];
    dst_csr[p] = d;
    const float4* s4 = (const float4*)&ea[(size_t)e * 16];
    float4* d4 = (float4*)&ea_csr[(size_t)p * 16];
    float4 t0 = s4[0], t1 = s4[1], t2 = s4[2], t3 = s4[3];
    d4[0] = t0; d4[1] = t1; d4[2] = t2; d4[3] = t3;
  }
}

// ---------------- h = X @ W (128x128) + b ----------------
__global__ __launch_bounds__(256) void gemm128_kernel(const float* __restrict__ X,
    const float* __restrict__ W, const float* __restrict__ bias,
    float* __restrict__ out, int M) {
  __shared__ float xs[128][33];
  int row0 = blockIdx.x * 32;
  int tid = threadIdx.x;
  for (int idx = tid; idx < 32 * 128; idx += 256) {
    int r = idx >> 7;
    int k = idx & 127;
    int row = row0 + r;
    xs[k][r] = (row < M) ? X[(size_t)row * 128 + k] : 0.0f;
  }
  __syncthreads();
  int tc = tid & 31, tr = tid >> 5;
  int c0 = tc * 4, r0 = tr * 4;
  float acc[4][4] = {};
#pragma unroll 4
  for (int k = 0; k < 128; k++) {
    float4 w = *(const float4*)&W[k * 128 + c0];
    float x0 = xs[k][r0], x1 = xs[k][r0 + 1], x2 = xs[k][r0 + 2], x3 = xs[k][r0 + 3];
    acc[0][0] += x0 * w.x; acc[0][1] += x0 * w.y; acc[0][2] += x0 * w.z; acc[0][3] += x0 * w.w;
    acc[1][0] += x1 * w.x; acc[1][1] += x1 * w.y; acc[1][2] += x1 * w.z; acc[1][3] += x1 * w.w;
    acc[2][0] += x2 * w.x; acc[2][1] += x2 * w.y; acc[2][2] += x2 * w.z; acc[2][3] += x2 * w.w;
    acc[3][0] += x3 * w.x; acc[3][1] += x3 * w.y; acc[3][2] += x3 * w.z; acc[3][3] += x3 * w.w;
  }
  float4 b4 = *(const float4*)&bias[c0];
  for (int r = 0; r < 4; r++) {
    int row = row0 + r0 + r;
    if (row < M) {
      float4 o;
      o.x = acc[r][0] + b4.x; o.y = acc[r][1] + b4.y;
      o.z = acc[r][2] + b4.z; o.w = acc[r][3] + b4.w;
      *(float4*)&out[(size_t)row * 128 + c0] = o;
    }
  }
}

// ---------------- ch[node*40 + {0..31}] = latent @ Wl3 + b ----------------
__global__ __launch_bounds__(256) void gemm32_kernel(const float* __restrict__ X,
    const float* __restrict__ W, const float* __restrict__ bias,
    float* __restrict__ ch, int M) {
  int t = blockIdx.x * 256 + threadIdx.x;
  int node = t >> 5, c = t & 31;
  if (node >= M) return;
  const float4* xp = (const float4*)&X[(size_t)node * 128];
  float acc = 0.f;
#pragma unroll
  for (int q = 0; q < 32; q++) {
    float4 x4 = xp[q];
    acc += x4.x * W[(q * 4 + 0) * 32 + c] + x4.y * W[(q * 4 + 1) * 32 + c]
         + x4.z * W[(q * 4 + 2) * 32 + c] + x4.w * W[(q * 4 + 3) * 32 + c];
  }
  ch[(size_t)node * 40 + c] = acc + bias[c];
}

// ---------------- ch[node*40 + 32] = latent @ Wl2 + b ----------------
__global__ __launch_bounds__(256) void gemv_kernel(const float* __restrict__ X,
    const float* __restrict__ w, const float* __restrict__ b0,
    float* __restrict__ ch, int M) {
  int wv = (blockIdx.x * 256 + threadIdx.x) >> 6;
  int lane = threadIdx.x & 63;
  if (wv >= M) return;
  float2 xv = *(const float2*)&X[(size_t)wv * 128 + lane * 2];
  float2 wvv = *(const float2*)&w[lane * 2];
  float v = xv.x * wvv.x + xv.y * wvv.y;
#pragma unroll
  for (int off = 32; off; off >>= 1) v += __shfl_xor(v, off);
  if (lane == 0) ch[(size_t)wv * 40 + 32] = v + b0[0];
}

// ---------------- layer-1 score pass: edge-parallel, half-wave/edge, reg-We ----------------
// No serial chain: every edge independent; We loaded once per wave (grid-stride).
__global__ __launch_bounds__(256) void escore1_kernel(const float* __restrict__ h,
    const int* __restrict__ src_csr, const int* __restrict__ dst_csr,
    const float* __restrict__ ea_csr,
    const float* __restrict__ We, const float* __restrict__ att,
    float* __restrict__ score, int E) {
  int tid = threadIdx.x;
  int lane = tid & 31;
  int c4 = lane * 4;
  f4 we[16];
#pragma unroll
  for (int k = 0; k < 16; k++) we[k] = *(const f4*)&We[k * 128 + c4];
  f4 attv = *(const f4*)&att[c4];
  int hw0 = (blockIdx.x * 256 + tid) >> 5;
  int hwTot = (gridDim.x * 256) >> 5;
  for (int p = hw0; p < E; p += hwTot) {
    int s = src_csr[p];
    int d = dst_csr[p];
    f4 hi = *(const f4*)&h[(size_t)d * 128 + c4];
    f4 hj = *(const f4*)&h[(size_t)s * 128 + c4];
    const f4* eap = (const f4*)&ea_csr[(size_t)p * 16];
    f4 a0 = eap[0], a1 = eap[1], a2 = eap[2], a3 = eap[3];
    f4 v = hi + hj;
    v += a0.x * we[0];  v += a0.y * we[1];  v += a0.z * we[2];  v += a0.w * we[3];
    v += a1.x * we[4];  v += a1.y * we[5];  v += a1.z * we[6];  v += a1.w * we[7];
    v += a2.x * we[8];  v += a2.y * we[9];  v += a2.z * we[10]; v += a2.w * we[11];
    v += a3.x * we[12]; v += a3.y * we[13]; v += a3.z * we[14]; v += a3.w * we[15];
    v.x = v.x >= 0.f ? v.x : NEG * v.x;
    v.y = v.y >= 0.f ? v.y : NEG * v.y;
    v.z = v.z >= 0.f ? v.z : NEG * v.z;
    v.w = v.w >= 0.f ? v.w : NEG * v.w;
    f4 pv = v * attv;
    float sc = (pv.x + pv.y) + (pv.z + pv.w);
#pragma unroll
    for (int off = 16; off; off >>= 1) sc += __shfl_xor(sc, off);
    if (lane == 0) score[p] = sc;
  }
}

// ---------------- layer-1 aggregate: half-wave/node, weights precomputed ----------------
// Gathers are independent of each other (weights known first) -> deep MLP.
__global__ __launch_bounds__(256) void agg1_kernel(const float* __restrict__ h,
    const int* __restrict__ src_csr, const int* __restrict__ row_start,
    const float* __restrict__ score, const float* __restrict__ bias,
    float* __restrict__ out, int N) {
  int tid = threadIdx.x;
  int hw = (blockIdx.x * 256 + tid) >> 5;
  int lane = tid & 31;
  if (hw >= N) return;
  int c4 = lane * 4;
  f4 bb = *(const f4*)&bias[c4];
  int start = row_start[hw];
  int deg = row_start[hw + 1] - start;
  if (deg == 0) {
    *(f4*)&out[(size_t)hw * 128 + c4] = bb;
    return;
  }
  // phase 1: exact max then exp-sum over streamed scores
  float mx = -INFINITY;
  for (int j = lane; j < deg; j += 32) mx = fmaxf(mx, score[start + j]);
#pragma unroll
  for (int off = 16; off; off >>= 1) mx = fmaxf(mx, __shfl_xor(mx, off));
  float se = 0.f;
  for (int j = lane; j < deg; j += 32) se += __expf(score[start + j] - mx);
#pragma unroll
  for (int off = 16; off; off >>= 1) se += __shfl_xor(se, off);
  float inv = 1.0f / (se + 1e-16f);
  // lane-resident first 32 weights + src ids
  float w_l = 0.f; int s_l = 0;
  if (lane < deg) {
    w_l = __expf(score[start + lane] - mx) * inv;
    s_l = src_csr[start + lane];
  }
  int dcap = deg < 32 ? deg : 32;
  f4 acc = (f4)0.f;
  for (int j0 = 0; j0 < deg; j0 += 4) {
    f4 hj[4]; float w[4];
#pragma unroll
    for (int t = 0; t < 4; t++) {
      int j = j0 + t;
      bool valid = (j < deg);
      int jc = valid ? j : j0;
      int s; float wt;
      if (jc < dcap) { s = __shfl(s_l, jc, 32); wt = __shfl(w_l, jc, 32); }
      else { s = src_csr[start + jc]; wt = __expf(score[start + jc] - mx) * inv; }
      w[t] = valid ? wt : 0.f;
      hj[t] = *(const f4*)&h[(size_t)s * 128 + c4];
    }
    acc += w[0] * hj[0] + w[1] * hj[1] + w[2] * hj[2] + w[3] * hj[3];
  }
  f4 o = acc + bb;
  *(f4*)&out[(size_t)hw * 128 + c4] = o;
}

// ---------------- layers 2+3 fused (wave/node, quarter-wave/edge, LDS weights,
//                  single combined ch gather stream) ----------------
__global__ __launch_bounds__(256) void fused23_kernel(
    const float* __restrict__ ch,
    const int* __restrict__ src_csr, const int* __restrict__ row_start,
    const float* __restrict__ ea_csr,
    const float* __restrict__ We3, const float* __restrict__ att3,
    const float* __restrict__ bias3, const float* __restrict__ We2,
    const float* __restrict__ att2, const float* __restrict__ bias2,
    float* __restrict__ out3, float* __restrict__ logits, int N) {
  __shared__ float We3S[512];
  __shared__ float att3S[32];
  __shared__ float We2S[16];
  int tid = threadIdx.x;
  for (int i = tid; i < 512; i += 256) We3S[i] = We3[i];
  if (tid < 32) att3S[tid] = att3[tid];
  if (tid < 16) We2S[tid] = We2[tid];
  __syncthreads();
  int wv = (blockIdx.x * 256 + tid) >> 6;
  int lane = tid & 63;
  if (wv >= N) return;
  int q4 = lane >> 4;
  int l16 = lane & 15;
  int c2 = l16 * 2;
  const f2* W3 = (const f2*)We3S;
  f2 at3 = *(const f2*)&att3S[c2];
  float a2s = att2[0];
  f2 bi3 = *(const f2*)&bias3[c2];
  int start = row_start[wv];
  int deg = row_start[wv + 1] - start;
  if (deg == 0) {
    if (lane < 16) *(f2*)&out3[(size_t)wv * 32 + c2] = bi3;
    if (lane == 0) logits[wv] = bias2[0];
    return;
  }
  f2 hi3 = *(const f2*)&ch[(size_t)wv * 40 + c2];
  float hi2 = ch[(size_t)wv * 40 + 32];
  int s_l = (lane < deg) ? src_csr[start + lane] : 0;
  int dcap = deg < 64 ? deg : 64;
  const float4* eap = (const float4*)&ea_csr[(size_t)start * 16];
  float m3 = -INFINITY, l3 = 0.f; f2 a3 = (f2)0.f;
  float m2 = -INFINITY, l2 = 0.f; float a2 = 0.f;
  for (int j = q4; j < deg; j += 4) {
    int s = (j < dcap) ? __shfl(s_l, j) : src_csr[start + j];
    f2 hj3 = *(const f2*)&ch[(size_t)s * 40 + c2];
    float h2s = ch[(size_t)s * 40 + 32];
    float4 c0 = eap[(size_t)j * 4 + 0];
    float4 c1 = eap[(size_t)j * 4 + 1];
    float4 cc2 = eap[(size_t)j * 4 + 2];
    float4 c3 = eap[(size_t)j * 4 + 3];
    f2 v = hi3 + hj3;
    v += c0.x * W3[0 * 16 + l16];  v += c0.y * W3[1 * 16 + l16];
    v += c0.z * W3[2 * 16 + l16];  v += c0.w * W3[3 * 16 + l16];
    v += c1.x * W3[4 * 16 + l16];  v += c1.y * W3[5 * 16 + l16];
    v += c1.z * W3[6 * 16 + l16];  v += c1.w * W3[7 * 16 + l16];
    v += cc2.x * W3[8 * 16 + l16]; v += cc2.y * W3[9 * 16 + l16];
    v += cc2.z * W3[10 * 16 + l16]; v += cc2.w * W3[11 * 16 + l16];
    v += c3.x * W3[12 * 16 + l16]; v += c3.y * W3[13 * 16 + l16];
    v += c3.z * W3[14 * 16 + l16]; v += c3.w * W3[15 * 16 + l16];
    v.x = v.x >= 0.f ? v.x : NEG * v.x;
    v.y = v.y >= 0.f ? v.y : NEG * v.y;
    float t3 = v.x * at3.x + v.y * at3.y;
#pragma unroll
    for (int off = 8; off; off >>= 1) t3 += __shfl_xor(t3, off);
    float v2 = hi2 + h2s;
    v2 += c0.x * We2S[0]  + c0.y * We2S[1]  + c0.z * We2S[2]  + c0.w * We2S[3];
    v2 += c1.x * We2S[4]  + c1.y * We2S[5]  + c1.z * We2S[6]  + c1.w * We2S[7];
    v2 += cc2.x * We2S[8] + cc2.y * We2S[9] + cc2.z * We2S[10] + cc2.w * We2S[11];
    v2 += c3.x * We2S[12] + c3.y * We2S[13] + c3.z * We2S[14] + c3.w * We2S[15];
    v2 = v2 >= 0.f ? v2 : NEG * v2;
    float t2 = v2 * a2s;
    float mn3 = fmaxf(m3, t3);
    float sc3 = __expf(m3 - mn3);
    float w3 = __expf(t3 - mn3);
    l3 = l3 * sc3 + w3;
    a3 = a3 * sc3 + w3 * hj3;
    m3 = mn3;
    float mn2 = fmaxf(m2, t2);
    float sc2 = __expf(m2 - mn2);
    float w2 = __expf(t2 - mn2);
    l2 = l2 * sc2 + w2;
    a2 = a2 * sc2 + w2 * h2s;
    m2 = mn2;
  }
#pragma unroll
  for (int off = 16; off <= 32; off <<= 1) {
    float m3o = __shfl_xor(m3, off), l3o = __shfl_xor(l3, off);
    float ax = __shfl_xor(a3.x, off), ay = __shfl_xor(a3.y, off);
    float M3 = fmaxf(m3, m3o);
    float sA = (m3 == -INFINITY) ? 0.f : __expf(m3 - M3);
    float sB = (m3o == -INFINITY) ? 0.f : __expf(m3o - M3);
    l3 = l3 * sA + l3o * sB;
    a3.x = a3.x * sA + ax * sB;
    a3.y = a3.y * sA + ay * sB;
    m3 = M3;
    float m2o = __shfl_xor(m2, off), l2o = __shfl_xor(l2, off);
    float az = __shfl_xor(a2, off);
    float M2 = fmaxf(m2, m2o);
    float tA = (m2 == -INFINITY) ? 0.f : __expf(m2 - M2);
    float tB = (m2o == -INFINITY) ? 0.f : __expf(m2o - M2);
    l2 = l2 * tA + l2o * tB;
    a2 = a2 * tA + az * tB;
    m2 = M2;
  }
  if (lane < 16) {
    f2 o;
    o.x = a3.x / (l3 + 1e-16f) + bi3.x;
    o.y = a3.y / (l3 + 1e-16f) + bi3.y;
    *(f2*)&out3[(size_t)wv * 32 + c2] = o;
  }
  if (lane == 0) logits[wv] = a2 / (l2 + 1e-16f) + bias2[0];
}

// ---------------- node categorical: 64-block partial + 1-wave final ----------------
#define NSB 64
__global__ __launch_bounds__(256) void node_partial_kernel(const float* __restrict__ logits,
    int N, uint32_t ka, uint32_t kb,
    float* __restrict__ pB, int* __restrict__ pI,
    float* __restrict__ pM, float* __restrict__ pL) {
  int chunk = (N + NSB - 1) / NSB;
  int s0 = blockIdx.x * chunk;
  int s1 = s0 + chunk; if (s1 > N) s1 = N;
  int tid = threadIdx.x;
  float best = -INFINITY; int bi = 0x7fffffff;
  float m = -INFINITY, l = 0.f;
  for (int i = s0 + tid; i < s1; i += 256) {
    float lg = logits[i];
    float mn = fmaxf(m, lg);
    l = l * __expf(m - mn) + __expf(lg - mn);
    m = mn;
    float v = lg + gumbel_part(ka, kb, (uint32_t)i);
    if (v > best) { best = v; bi = i; }
  }
  __shared__ float sb[256], sm[256], sl[256];
  __shared__ int si[256];
  sb[tid] = best; si[tid] = bi; sm[tid] = m; sl[tid] = l;
  __syncthreads();
  for (int s = 128; s; s >>= 1) {
    if (tid < s) {
      if (sb[tid + s] > sb[tid] || (sb[tid + s] == sb[tid] && si[tid + s] < si[tid])) {
        sb[tid] = sb[tid + s]; si[tid] = si[tid + s];
      }
      float M = fmaxf(sm[tid], sm[tid + s]);
      float t0 = (sm[tid] == -INFINITY) ? 0.f : sl[tid] * __expf(sm[tid] - M);
      float t1 = (sm[tid + s] == -INFINITY) ? 0.f : sl[tid + s] * __expf(sm[tid + s] - M);
      sm[tid] = M; sl[tid] = t0 + t1;
    }
    __syncthreads();
  }
  if (tid == 0) { pB[blockIdx.x] = sb[0]; pI[blockIdx.x] = si[0]; pM[blockIdx.x] = sm[0]; pL[blockIdx.x] = sl[0]; }
}

__global__ __launch_bounds__(64) void node_final_kernel(const float* __restrict__ logits,
    const float* __restrict__ pB, const int* __restrict__ pI,
    const float* __restrict__ pM, const float* __restrict__ pL,
    float* __restrict__ scal) {
  int lane = threadIdx.x;
  float best = pB[lane]; int bi = pI[lane];
  float m = pM[lane]; float l = pL[lane];
#pragma unroll
  for (int off = 32; off; off >>= 1) {
    float ob = __shfl_xor(best, off); int oi = __shfl_xor(bi, off);
    if (ob > best || (ob == best && oi < bi)) { best = ob; bi = oi; }
    float om = __shfl_xor(m, off); float ol = __shfl_xor(l, off);
    float M = fmaxf(m, om);
    float t0 = (m == -INFINITY) ? 0.f : l * __expf(m - M);
    float t1 = (om == -INFINITY) ? 0.f : ol * __expf(om - M);
    m = M; l = t0 + t1;
  }
  if (lane == 0) {
    ((int*)scal)[0] = bi;
    scal[3] = logits[bi] - (m + logf(l));
  }
}

// ---------------- action categorical + output ----------------
__global__ __launch_bounds__(64) void action_kernel(const float* __restrict__ out3,
    const float* __restrict__ scal, uint32_t ka, uint32_t kb,
    float* __restrict__ dout, int out_size) {
  int lane = threadIdx.x;
  int sel = ((const int*)scal)[0];
  float v = -INFINITY, noisy = -INFINITY;
  if (lane < 32) {
    v = out3[(size_t)sel * 32 + lane];
    noisy = v + gumbel_part(ka, kb, (uint32_t)lane);
  }
  int idx = lane;
  float nv = noisy;
#pragma unroll
  for (int off = 32; off; off >>= 1) {
    float ov = __shfl_xor(nv, off);
    int oi = __shfl_xor(idx, off);
    if (ov > nv || (ov == nv && oi < idx)) { nv = ov; idx = oi; }
  }
  float vm = v;
#pragma unroll
  for (int off = 32; off; off >>= 1) vm = fmaxf(vm, __shfl_xor(vm, off));
  float ex = (lane < 32) ? expf(v - vm) : 0.f;
#pragma unroll
  for (int off = 32; off; off >>= 1) ex += __shfl_xor(ex, off);
  float vsel = __shfl(v, idx);
  if (lane == 0) {
    float action_lp = vsel - vm - logf(ex);
    dout[0] = (float)sel;
    dout[1] = (float)idx;
    dout[2] = scal[3] + action_lp;
  }
  for (int i = 3 + lane; i < out_size; i += 64) dout[i] = 0.f;
}

extern "C" void kernel_launch(void* const* d_in, const int* in_sizes, int n_in,
                              void* d_out, int out_size, void* d_ws, size_t ws_size,
                              hipStream_t stream) {
  const float* x     = (const float*)d_in[0];
  const int*   ei    = (const int*)d_in[1];
  const float* ea    = (const float*)d_in[2];
  const float* Wl1   = (const float*)d_in[3];
  const float* bl1   = (const float*)d_in[4];
  const float* We1   = (const float*)d_in[5];
  const float* att1  = (const float*)d_in[6];
  const float* bias1 = (const float*)d_in[7];
  const float* Wl2   = (const float*)d_in[8];
  const float* bl2   = (const float*)d_in[9];
  const float* We2   = (const float*)d_in[10];
  const float* att2  = (const float*)d_in[11];
  const float* bias2 = (const float*)d_in[12];
  const float* Wl3   = (const float*)d_in[13];
  const float* bl3   = (const float*)d_in[14];
  const float* We3   = (const float*)d_in[15];
  const float* att3  = (const float*)d_in[16];
  const float* bias3 = (const float*)d_in[17];
  int N = in_sizes[0] / 128;
  int E = in_sizes[1] / 2;
  float* out = (float*)d_out;

  char* p = (char*)d_ws;
  auto alloc = [&](size_t bytes) -> char* {
    char* r = p; p += (bytes + 255) & ~(size_t)255; return r;
  };
  float* h1      = (float*)alloc((size_t)N * 128 * 4);
  float* latent  = (float*)alloc((size_t)N * 128 * 4);
  float* ch      = (float*)alloc((size_t)N * 40 * 4);   // h3 dims 0-31, h2 at 32
  float* logits  = (float*)alloc((size_t)N * 4);
  float* out3    = (float*)alloc((size_t)N * 32 * 4);
  int* counts    = (int*)alloc((size_t)N * 4);
  int* row_start = (int*)alloc((size_t)(N + 1) * 4);
  int* cursor    = (int*)alloc((size_t)N * 4);
  int* src_csr   = (int*)alloc((size_t)E * 4);
  int* dst_csr   = (int*)alloc((size_t)E * 4);
  float* ea_csr  = (float*)alloc((size_t)E * 16 * 4);
  float* score   = (float*)alloc((size_t)E * 4);
  int* bsum      = (int*)alloc(SCB * 4);
  int* boff      = (int*)alloc(SCB * 4);
  float* pB      = (float*)alloc(NSB * 4);
  int*   pI      = (int*)alloc(NSB * 4);
  float* pM      = (float*)alloc(NSB * 4);
  float* pL      = (float*)alloc(NSB * 4);
  float* scal    = (float*)alloc(64);
  (void)ws_size; (void)n_in;

  // JAX PRNG (partitionable): key(42)=(0,42); subkey_i = TF(key,(0,i))
  uint32_t k1a, k1b, k2a, k2b;
  threefry2x32(0u, 42u, 0u, 0u, &k1a, &k1b);
  threefry2x32(0u, 42u, 0u, 1u, &k2a, &k2b);

  int chunk = (N + SCB - 1) / SCB;

  hipMemsetAsync(counts, 0, (size_t)N * 4, stream);
  count_kernel<<<(E + 255) / 256, 256, 0, stream>>>(ei, E, counts);
  scan_partial_kernel<<<SCB, 256, 0, stream>>>(counts, N, chunk, bsum);
  scan_offsets_kernel<<<1, 256, 0, stream>>>(bsum, boff, row_start, N);
  scan_apply_kernel<<<SCB, 256, 0, stream>>>(counts, boff, N, chunk, row_start, cursor);
  scatter_kernel<<<(E + 255) / 256, 256, 0, stream>>>(ei, ea, E, cursor,
                                                      src_csr, dst_csr, ea_csr);

  gemm128_kernel<<<(N + 31) / 32, 256, 0, stream>>>(x, Wl1, bl1, h1, N);
  escore1_kernel<<<2048, 256, 0, stream>>>(h1, src_csr, dst_csr, ea_csr,
                                           We1, att1, score, E);
  agg1_kernel<<<(N + 7) / 8, 256, 0, stream>>>(h1, src_csr, row_start, score,
                                               bias1, latent, N);

  gemm32_kernel<<<((size_t)N * 32 + 255) / 256, 256, 0, stream>>>(latent, Wl3, bl3, ch, N);
  gemv_kernel<<<(N + 3) / 4, 256, 0, stream>>>(latent, Wl2, bl2, ch, N);

  fused23_kernel<<<(N + 3) / 4, 256, 0, stream>>>(ch, src_csr, row_start, ea_csr,
                                                  We3, att3, bias3, We2, att2, bias2,
                                                  out3, logits, N);

  node_partial_kernel<<<NSB, 256, 0, stream>>>(logits, N, k1a, k1b, pB, pI, pM, pL);
  node_final_kernel<<<1, 64, 0, stream>>>(logits, pB, pI, pM, pL, scal);
  action_kernel<<<1, 64, 0, stream>>>(out3, scal, k2a, k2b, out, out_size);
}